// Round 21
// baseline (4362.528 us; speedup 1.0000x reference)
//
#include <hip/hip_runtime.h>
#include <hip/hip_bf16.h>
#include <math.h>

// Fused LM-head cross-entropy: loss = mean_valid( logsumexp(x@W^T) - logit[y] )
// N=4096 tokens, H=4096 hidden, V=128000 vocab.
//
// Round 21: R20 (best, 2.52 ms) + T5 s_setprio around each substep's MFMA
// cluster. 4 waves/SIMD free-run between barriers (role diversity: reads vs
// MFMA) -- the exact regime where setprio pays (catalog T5). A-reads stay
// outside the raised-priority region so low-prio waves keep the LDS pipe fed.
// Everything else identical to R20: A = fp8 e4m3 (X), B = fp4 e2m1 (W x64),
// 16-wave 256^2, dbuf, vmcnt(4) ledger, __launch_bounds__(1024,4), identity
// MX scales, exact 2^-6 epilogue unscale.

#define N_ROWS 4096
#define H_DIM  4096
#define V_DIM  128000
#define BM 256
#define BN 256
#define NT_N (N_ROWS / BM)      // 16
#define NT_V (V_DIM / BN)       // 500
#define NKT  (H_DIM / 128)      // 32 A-K-tiles (128 elems); B super-tiles = 16
#define IGNORE_INDEX (-100)

typedef __attribute__((ext_vector_type(4))) int   i32x4;
typedef __attribute__((ext_vector_type(8))) int   i32x8;
typedef __attribute__((ext_vector_type(4))) float f32x4;
typedef __attribute__((ext_vector_type(16))) float f32x16;
typedef const __attribute__((address_space(1))) unsigned int* gas1_u32;
typedef __attribute__((address_space(3))) unsigned int* las3_u32;

// ---------------- exact f32 -> e4m3fn (OCP), RNE, saturating ----------------
__device__ __forceinline__ unsigned f2e4m3(float f) {
    unsigned u = __float_as_uint(f);
    unsigned s = (u >> 24) & 0x80u;
    float af = __uint_as_float(u & 0x7FFFFFFFu);
    unsigned code;
    if (af >= 0.015625f) {
        if (af > 448.f) af = 448.f;
        unsigned v = __float_as_uint(af);
        v += 0x7FFFFu + ((v >> 20) & 1u);
        unsigned m3 = (v >> 20) & 7u;
        int E = (int)(v >> 23) - 127;
        if (E > 8) { E = 8; m3 = 6u; }
        code = (unsigned)((E + 7) << 3) | m3;
    } else {
        code = (unsigned)rintf(af * 512.0f);
    }
    return s | code;
}

__global__ void cvt_f32_fp8_kernel(const float* __restrict__ in,
                                   unsigned char* __restrict__ out, size_t n, float scale)
{
    size_t i = ((size_t)blockIdx.x * blockDim.x + threadIdx.x) * 8;
    size_t stride = (size_t)gridDim.x * blockDim.x * 8;
    for (; i < n; i += stride) {
        f32x4 a = *(const f32x4*)(in + i);
        f32x4 b = *(const f32x4*)(in + i + 4);
        unsigned long long o;
        o  = (unsigned long long)f2e4m3(a.x * scale);
        o |= (unsigned long long)f2e4m3(a.y * scale) << 8;
        o |= (unsigned long long)f2e4m3(a.z * scale) << 16;
        o |= (unsigned long long)f2e4m3(a.w * scale) << 24;
        o |= (unsigned long long)f2e4m3(b.x * scale) << 32;
        o |= (unsigned long long)f2e4m3(b.y * scale) << 40;
        o |= (unsigned long long)f2e4m3(b.z * scale) << 48;
        o |= (unsigned long long)f2e4m3(b.w * scale) << 56;
        *(unsigned long long*)(out + i) = o;
    }
}

// ---------------- f32 -> e2m1 (fp4), ~RNE, saturating ----------------
__device__ __forceinline__ unsigned f2e2m1(float f) {
    unsigned s = (__float_as_uint(f) >> 28) & 0x8u;
    float af = fabsf(f);
    unsigned m;
    if      (af <= 0.25f) m = 0;
    else if (af <  0.75f) m = 1;
    else if (af <= 1.25f) m = 2;
    else if (af <  1.75f) m = 3;
    else if (af <= 2.50f) m = 4;
    else if (af <  3.50f) m = 5;
    else if (af <= 5.00f) m = 6;
    else                  m = 7;
    return s | m;
}

__global__ void cvt_f32_fp4_kernel(const float* __restrict__ in,
                                   unsigned char* __restrict__ out, size_t n, float scale)
{
    size_t i = ((size_t)blockIdx.x * blockDim.x + threadIdx.x) * 8;
    size_t stride = (size_t)gridDim.x * blockDim.x * 8;
    for (; i < n; i += stride) {
        f32x4 a = *(const f32x4*)(in + i);
        f32x4 b = *(const f32x4*)(in + i + 4);
        unsigned w;
        w  = f2e2m1(a.x * scale);
        w |= f2e2m1(a.y * scale) << 4;
        w |= f2e2m1(a.z * scale) << 8;
        w |= f2e2m1(a.w * scale) << 12;
        w |= f2e2m1(b.x * scale) << 16;
        w |= f2e2m1(b.y * scale) << 20;
        w |= f2e2m1(b.z * scale) << 24;
        w |= f2e2m1(b.w * scale) << 28;
        __builtin_nontemporal_store(w, (unsigned*)(out + (i >> 1)));
    }
}

#define BAR()    asm volatile("s_barrier" ::: "memory")
#define WAITV4() asm volatile("s_waitcnt vmcnt(4)" ::: "memory")
#define SETP1()  __builtin_amdgcn_s_setprio(1)
#define SETP0()  __builtin_amdgcn_s_setprio(0)
#define SCL1 ((int)0x7F7F7F7F)   // E8M0 127 = 2^0 in every byte (identity)

// 32B fp8 fragment read: low 16B at off, high 16B at off^16
__device__ __forceinline__ i32x8 rd32(const char* base, int off) {
    i32x8 r;
    *(i32x4*)&r       = *(const i32x4*)(base + off);
    *((i32x4*)&r + 1) = *(const i32x4*)(base + (off ^ 16));
    return r;
}

// pad a 16B fp4 fragment into the low half of a v8i32 operand
__device__ __forceinline__ i32x8 pad4(i32x4 v) {
    i32x8 r;
    r[0] = v[0]; r[1] = v[1]; r[2] = v[2]; r[3] = v[3];
    r[4] = 0; r[5] = 0; r[6] = 0; r[7] = 0;
    return r;
}

// ------------- 256^2 16-wave mixed fp8(A)/fp4(B) GEMM, static-indexed -------------
__global__ __launch_bounds__(1024, 4)
void lmce_gemm256_kernel(const unsigned char* __restrict__ Xq, const unsigned char* __restrict__ Wq,
                         float* __restrict__ pm, float* __restrict__ pl)
{
    // A: [buf][256 rows][128B] (one 128-elem fp8 K-tile) = 32KB x2
    // B: [buf][256 rows][128B] (one 256-elem fp4 super-tile) = 32KB x2
    __shared__ __align__(16) char lsA[2][256 * 128];
    __shared__ __align__(16) char lsB[2][256 * 128];
    __shared__ float red_m[4][BM];
    __shared__ float red_l[4][BM];
    const char* lsAc = (const char*)lsA;
    const char* lsBc = (const char*)lsB;

    // bijective XCD swizzle: nwg = 8000, divisible by 8
    const int nwg = NT_N * NT_V;
    int orig = blockIdx.x;
    int wg = (orig & 7) * (nwg >> 3) + (orig >> 3);
    int vtile = wg / NT_N;
    int ntile = wg - vtile * NT_N;

    int tid  = threadIdx.x;
    int lane = tid & 63;
    int w    = tid >> 6;          // 0..15
    int wr = w >> 2;              // 0..3 : 64-row A strip
    int wc = w & 3;               // 0..3 : 64-col B strip
    int l31 = lane & 31;
    int kb  = (lane >> 5) * 32;   // A k-byte base within a 64-elem substep
    int kh  = lane >> 5;          // B k-half within a 64-elem substep

    // staging row map: row = j*128 + w*8 + (lane>>3); 16B chunk (lane&7),
    // source col pre-swizzled with the read XOR.
    int scolb = (((lane & 7) ^ ((lane >> 3) & 7)) * 16);
    const char* gAr = (const char*)Xq + (size_t)(ntile * BM + w * 8 + (lane >> 3)) * 4096 + scolb;
    const char* gBr = (const char*)Wq + (size_t)(vtile * BN + w * 8 + (lane >> 3)) * 2048 + scolb;

    // A fragment offsets (fp8): substep ks in 0..1 of the 128-elem tile
    int offA[2][2];
    #pragma unroll
    for (int mi = 0; mi < 2; ++mi)
        #pragma unroll
        for (int ks = 0; ks < 2; ++ks) {
            int rowA = wr * 64 + mi * 32 + l31;
            offA[mi][ks] = rowA * 128 + ((kb + ks * 64) ^ ((rowA & 7) << 4));
        }
    // B fragment offsets (fp4): slot q in 0..3 (64-elem substeps of 256-elem tile)
    int offB[2][4];
    #pragma unroll
    for (int ni = 0; ni < 2; ++ni)
        #pragma unroll
        for (int q = 0; q < 4; ++q) {
            int rowB = wc * 64 + ni * 32 + l31;
            offB[ni][q] = rowB * 128 + ((q * 32 + kh * 16) ^ ((rowB & 7) << 4));
        }

    f32x16 acc[2][2];
    #pragma unroll
    for (int i = 0; i < 2; ++i)
        #pragma unroll
        for (int j = 0; j < 2; ++j)
            #pragma unroll
            for (int r = 0; r < 16; ++r)
                acc[i][j][r] = 0.f;

    #define STAGE_A(BUF, KT)                                                           \
        { _Pragma("unroll")                                                            \
          for (int j_ = 0; j_ < 2; ++j_)                                               \
              __builtin_amdgcn_global_load_lds(                                        \
                  (gas1_u32)(gAr + (size_t)j_ * 524288 + (size_t)(KT) * 128),          \
                  (las3_u32)((char*)lsA + (BUF) * 32768 + j_ * 16384 + w * 1024),      \
                  16, 0, 0); }
    #define STAGE_B(BUF, S)                                                            \
        { _Pragma("unroll")                                                            \
          for (int j_ = 0; j_ < 2; ++j_)                                               \
              __builtin_amdgcn_global_load_lds(                                        \
                  (gas1_u32)(gBr + (size_t)j_ * 262144 + (size_t)(S) * 128),           \
                  (las3_u32)((char*)lsB + (BUF) * 32768 + j_ * 16384 + w * 1024),      \
                  16, 0, 0); }

    // one K=64 substep: A frags (ks static), B slot (q static), 4 MFMAs.
    // T5: raise priority only around the MFMA cluster.
    #define SUBSTEP(AbP, BbP, KS, Q)                                                   \
        {                                                                              \
            i32x8 a0 = rd32(AbP, offA[0][KS]);                                         \
            i32x8 a1 = rd32(AbP, offA[1][KS]);                                         \
            SETP1();                                                                   \
            {                                                                          \
                i32x8 b0 = pad4(*(const i32x4*)((BbP) + offB[0][Q]));                  \
                acc[0][0] = __builtin_amdgcn_mfma_scale_f32_32x32x64_f8f6f4(a0, b0, acc[0][0], 0, 4, 0, SCL1, 0, SCL1); \
                acc[1][0] = __builtin_amdgcn_mfma_scale_f32_32x32x64_f8f6f4(a1, b0, acc[1][0], 0, 4, 0, SCL1, 0, SCL1); \
            }                                                                          \
            {                                                                          \
                i32x8 b1 = pad4(*(const i32x4*)((BbP) + offB[1][Q]));                  \
                acc[0][1] = __builtin_amdgcn_mfma_scale_f32_32x32x64_f8f6f4(a0, b1, acc[0][1], 0, 4, 0, SCL1, 0, SCL1); \
                acc[1][1] = __builtin_amdgcn_mfma_scale_f32_32x32x64_f8f6f4(a1, b1, acc[1][1], 0, 4, 0, SCL1, 0, SCL1); \
            }                                                                          \
            SETP0();                                                                   \
        }

    // prologue: A0, B0, A1, B1 (8 insts); vmcnt(4) retires A0,B0
    STAGE_A(0, 0); STAGE_B(0, 0);
    STAGE_A(1, 1); STAGE_B(1, 1);
    WAITV4();
    BAR();

    for (int t = 0; t < NKT; t += 2) {
        int s  = t >> 1;                       // B super-tile index
        const char* BbP = lsBc + (s & 1) * 32768;   // runtime base (ptr math, ok)

        // ---- even iteration (tile t): A buf0, B half 0 (q = 0,1)
        SUBSTEP(lsAc,        BbP, 0, 0);
        SUBSTEP(lsAc,        BbP, 1, 1);
        BAR();                                 // all reads of A buf0 retired
        {
            int ta = (t + 2 < NKT) ? t + 2 : NKT - 1;
            STAGE_A(0, ta);                    // A(t+2) -> retired buf0
        }
        // outstanding: A(t+1)2, B(s+1)2, A(t+2)2 = 6 -> vmcnt(4) retires A(t+1)
        WAITV4();
        BAR();

        // ---- odd iteration (tile t+1): A buf1, B half 1 (q = 2,3)
        SUBSTEP(lsAc + 32768, BbP, 0, 2);
        SUBSTEP(lsAc + 32768, BbP, 1, 3);
        BAR();                                 // reads of A buf1 + B buf retired
        {
            int ta = (t + 3 < NKT) ? t + 3 : NKT - 1;
            STAGE_A(1, ta);                    // A(t+3) -> retired buf1
            int s2 = (s + 2 < 16) ? s + 2 : 15;
            STAGE_B(s & 1, s2);                // B(s+2) -> retired B buf
        }
        // outstanding: B(s+1)2, A(t+2)2, A(t+3)2, B(s+2)2 = 8
        // vmcnt(4) retires B(s+1)+A(t+2): exactly what tile t+2 needs.
        WAITV4();
        BAR();
    }

    __syncthreads();   // full drain before epilogue

    // Epilogue: per-row max and sumexp over this block's 256 cols.
    // 32x32 C/D layout: col = lane&31, row = (r&3) + 8*(r>>2) + 4*(lane>>5).
    // Unscale logits by 2^-6 (W was stored x64) -- exact power of two.
    const float inv64 = 0.015625f;
    #pragma unroll
    for (int mi = 0; mi < 2; ++mi) {
        #pragma unroll
        for (int r = 0; r < 16; ++r) {
            float v0 = acc[mi][0][r] * inv64;
            float v1 = acc[mi][1][r] * inv64;
            float mx = fmaxf(v0, v1);
            #pragma unroll
            for (int s = 1; s < 32; s <<= 1)
                mx = fmaxf(mx, __shfl_xor(mx, s, 64));
            float se = __expf(v0 - mx) + __expf(v1 - mx);
            #pragma unroll
            for (int s = 1; s < 32; s <<= 1)
                se += __shfl_xor(se, s, 64);
            if (l31 == 0) {
                int rloc = wr * 64 + mi * 32 + (r & 3) + 8 * (r >> 2) + 4 * (lane >> 5);
                red_m[wc][rloc] = mx;
                red_l[wc][rloc] = se;
            }
        }
    }
    __syncthreads();
    if (tid < BM) {
        float mm = red_m[0][tid], ll = red_l[0][tid];
        #pragma unroll
        for (int p = 1; p < 4; ++p) {
            float m2 = red_m[p][tid], l2 = red_l[p][tid];
            float m3 = fmaxf(mm, m2);
            ll = ll * __expf(mm - m3) + l2 * __expf(m2 - m3);
            mm = m3;
        }
        size_t idx = (size_t)vtile * N_ROWS + (size_t)(ntile * BM + tid);
        pm[idx] = mm;
        pl[idx] = ll;
    }
    #undef STAGE_A
    #undef STAGE_B
    #undef SUBSTEP
}

// tgt[row] = dot(x[row], W[y[row]]) in fp32 (exact vs reference)
__global__ void lmce_tgt_kernel(const float* __restrict__ X, const float* __restrict__ W,
                                const int* __restrict__ y, float* __restrict__ tgt)
{
    int row = blockIdx.x;
    int tid = threadIdx.x;
    int yv = y[row];
    float s = 0.f;
    if (yv >= 0 && yv < V_DIM) {
        const float* xr = X + (size_t)row * H_DIM;
        const float* wrow = W + (size_t)yv * H_DIM;
        #pragma unroll
        for (int j = 0; j < 4; ++j) {
            int idx = (tid + j * 256) * 4;
            f32x4 a = *(const f32x4*)(xr + idx);
            f32x4 b = *(const f32x4*)(wrow + idx);
            s += a.x * b.x + a.y * b.y + a.z * b.z + a.w * b.w;
        }
    }
    #pragma unroll
    for (int sh = 1; sh < 64; sh <<= 1) s += __shfl_xor(s, sh, 64);
    __shared__ float sred[4];
    if ((tid & 63) == 0) sred[tid >> 6] = s;
    __syncthreads();
    if (tid == 0) tgt[row] = sred[0] + sred[1] + sred[2] + sred[3];
}

// merge NT_V per-vtile (m,l) partials per row -> lse[row]
__global__ void lmce_lse_kernel(const float* __restrict__ pm, const float* __restrict__ pl,
                                float* __restrict__ lse)
{
    int tid = threadIdx.x;
    int row = blockIdx.x * 64 + (tid & 63);
    int part = tid >> 6;               // 0..3, each scans NT_V/4 = 125 vtiles
    const int per = NT_V / 4;
    float m = -INFINITY, l = 0.f;
    for (int vt = part * per; vt < (part + 1) * per; ++vt) {
        size_t idx = (size_t)vt * N_ROWS + row;
        float m2 = pm[idx], l2 = pl[idx];
        float mm = fmaxf(m, m2);
        l = l * __expf(m - mm) + l2 * __expf(m2 - mm);
        m = mm;
    }
    __shared__ float sm[4][64], sl[4][64];
    sm[part][tid & 63] = m;
    sl[part][tid & 63] = l;
    __syncthreads();
    if (tid < 64) {
        float M = sm[0][tid], L = sl[0][tid];
        #pragma unroll
        for (int p = 1; p < 4; ++p) {
            float m2 = sm[p][tid], l2 = sl[p][tid];
            float mm = fmaxf(M, m2);
            L = L * __expf(M - mm) + l2 * __expf(m2 - mm);
            M = mm;
        }
        lse[blockIdx.x * 64 + tid] = M + logf(L);
    }
}

__global__ void lmce_final_kernel(const float* __restrict__ lse, const float* __restrict__ tgt,
                                  const int* __restrict__ y, float* __restrict__ out)
{
    int tid = threadIdx.x;
    float s = 0.f, c = 0.f;
    for (int i = tid; i < N_ROWS; i += 256) {
        if (y[i] != IGNORE_INDEX) {
            s += lse[i] - tgt[i];
            c += 1.f;
        }
    }
    #pragma unroll
    for (int sh = 1; sh < 64; sh <<= 1) {
        s += __shfl_xor(s, sh, 64);
        c += __shfl_xor(c, sh, 64);
    }
    __shared__ float ss[4], cc[4];
    if ((tid & 63) == 0) { ss[tid >> 6] = s; cc[tid >> 6] = c; }
    __syncthreads();
    if (tid == 0) {
        float S = ss[0] + ss[1] + ss[2] + ss[3];
        float C = cc[0] + cc[1] + cc[2] + cc[3];
        out[0] = S / fmaxf(C, 1.f);
    }
}

extern "C" void kernel_launch(void* const* d_in, const int* in_sizes, int n_in,
                              void* d_out, int out_size, void* d_ws, size_t ws_size,
                              hipStream_t stream)
{
    const float* X = (const float*)d_in[0];   // [4096, 4096] fp32
    const int*   y = (const int*)d_in[1];     // [4096] labels
    const float* W = (const float*)d_in[2];   // [128000, 4096] fp32
    float* out = (float*)d_out;

    char* ws = (char*)d_ws;
    const size_t OFF_PL  = 16384000;
    const size_t OFF_TGT = 32768000;
    const size_t OFF_LSE = 32784384;
    const size_t OFF_XQ  = 32800768;                 // 16 MB fp8 X
    const size_t OFF_WQ  = OFF_XQ + 16777216;        // 256 MB fp4 W (x64 scaled)

    float* pm  = (float*)ws;
    float* pl  = (float*)(ws + OFF_PL);
    float* tgt = (float*)(ws + OFF_TGT);
    float* lse = (float*)(ws + OFF_LSE);
    unsigned char* Xq = (unsigned char*)(ws + OFF_XQ);
    unsigned char* Wq = (unsigned char*)(ws + OFF_WQ);

    cvt_f32_fp4_kernel<<<4096, 256, 0, stream>>>(W, Wq, (size_t)V_DIM * H_DIM, 64.0f);
    cvt_f32_fp8_kernel<<<512, 256, 0, stream>>>(X, Xq, (size_t)N_ROWS * H_DIM, 1.0f);
    lmce_gemm256_kernel<<<NT_N * NT_V, 1024, 0, stream>>>(Xq, Wq, pm, pl);
    lmce_tgt_kernel<<<N_ROWS, 256, 0, stream>>>(X, W, y, tgt);
    lmce_lse_kernel<<<N_ROWS / 64, 256, 0, stream>>>(pm, pl, lse);
    lmce_final_kernel<<<1, 256, 0, stream>>>(lse, tgt, y, out);
}

// Round 22
// 2522.334 us; speedup vs baseline: 1.7296x; 1.7296x over previous
//
#include <hip/hip_runtime.h>
#include <hip/hip_bf16.h>
#include <math.h>

// Fused LM-head cross-entropy: loss = mean_valid( logsumexp(x@W^T) - logit[y] )
// N=4096 tokens, H=4096 hidden, V=128000 vocab.
//
// FINAL (Round 22 = R18/R20, reproduced twice at 2.52 ms): mixed-precision
// MX GEMM. A = fp8 e4m3 (X), B = fp4 e2m1 (W, x64-scaled; exact 2^-6 unscale
// in epilogue). 16-wave 256^2 tile, double-buffered LDS via global_load_lds
// (linear dest + pre-swizzled source + XOR-swizzled reads), counted vmcnt(4)
// ledger (never drain to 0 in-loop), bijective XCD swizzle, identity E8M0
// scales. __launch_bounds__(1024,4) pins the reg budget (R21 showed even a
// setprio hint perturbs regalloc over the 64-VGPR cliff into spill).

#define N_ROWS 4096
#define H_DIM  4096
#define V_DIM  128000
#define BM 256
#define BN 256
#define NT_N (N_ROWS / BM)      // 16
#define NT_V (V_DIM / BN)       // 500
#define NKT  (H_DIM / 128)      // 32 A-K-tiles (128 elems); B super-tiles = 16
#define IGNORE_INDEX (-100)

typedef __attribute__((ext_vector_type(4))) int   i32x4;
typedef __attribute__((ext_vector_type(8))) int   i32x8;
typedef __attribute__((ext_vector_type(4))) float f32x4;
typedef __attribute__((ext_vector_type(16))) float f32x16;
typedef const __attribute__((address_space(1))) unsigned int* gas1_u32;
typedef __attribute__((address_space(3))) unsigned int* las3_u32;

// ---------------- exact f32 -> e4m3fn (OCP), RNE, saturating ----------------
__device__ __forceinline__ unsigned f2e4m3(float f) {
    unsigned u = __float_as_uint(f);
    unsigned s = (u >> 24) & 0x80u;
    float af = __uint_as_float(u & 0x7FFFFFFFu);
    unsigned code;
    if (af >= 0.015625f) {
        if (af > 448.f) af = 448.f;
        unsigned v = __float_as_uint(af);
        v += 0x7FFFFu + ((v >> 20) & 1u);
        unsigned m3 = (v >> 20) & 7u;
        int E = (int)(v >> 23) - 127;
        if (E > 8) { E = 8; m3 = 6u; }
        code = (unsigned)((E + 7) << 3) | m3;
    } else {
        code = (unsigned)rintf(af * 512.0f);
    }
    return s | code;
}

__global__ void cvt_f32_fp8_kernel(const float* __restrict__ in,
                                   unsigned char* __restrict__ out, size_t n, float scale)
{
    size_t i = ((size_t)blockIdx.x * blockDim.x + threadIdx.x) * 8;
    size_t stride = (size_t)gridDim.x * blockDim.x * 8;
    for (; i < n; i += stride) {
        f32x4 a = *(const f32x4*)(in + i);
        f32x4 b = *(const f32x4*)(in + i + 4);
        unsigned long long o;
        o  = (unsigned long long)f2e4m3(a.x * scale);
        o |= (unsigned long long)f2e4m3(a.y * scale) << 8;
        o |= (unsigned long long)f2e4m3(a.z * scale) << 16;
        o |= (unsigned long long)f2e4m3(a.w * scale) << 24;
        o |= (unsigned long long)f2e4m3(b.x * scale) << 32;
        o |= (unsigned long long)f2e4m3(b.y * scale) << 40;
        o |= (unsigned long long)f2e4m3(b.z * scale) << 48;
        o |= (unsigned long long)f2e4m3(b.w * scale) << 56;
        *(unsigned long long*)(out + i) = o;
    }
}

// ---------------- f32 -> e2m1 (fp4), ~RNE, saturating ----------------
__device__ __forceinline__ unsigned f2e2m1(float f) {
    unsigned s = (__float_as_uint(f) >> 28) & 0x8u;
    float af = fabsf(f);
    unsigned m;
    if      (af <= 0.25f) m = 0;
    else if (af <  0.75f) m = 1;
    else if (af <= 1.25f) m = 2;
    else if (af <  1.75f) m = 3;
    else if (af <= 2.50f) m = 4;
    else if (af <  3.50f) m = 5;
    else if (af <= 5.00f) m = 6;
    else                  m = 7;
    return s | m;
}

__global__ void cvt_f32_fp4_kernel(const float* __restrict__ in,
                                   unsigned char* __restrict__ out, size_t n, float scale)
{
    size_t i = ((size_t)blockIdx.x * blockDim.x + threadIdx.x) * 8;
    size_t stride = (size_t)gridDim.x * blockDim.x * 8;
    for (; i < n; i += stride) {
        f32x4 a = *(const f32x4*)(in + i);
        f32x4 b = *(const f32x4*)(in + i + 4);
        unsigned w;
        w  = f2e2m1(a.x * scale);
        w |= f2e2m1(a.y * scale) << 4;
        w |= f2e2m1(a.z * scale) << 8;
        w |= f2e2m1(a.w * scale) << 12;
        w |= f2e2m1(b.x * scale) << 16;
        w |= f2e2m1(b.y * scale) << 20;
        w |= f2e2m1(b.z * scale) << 24;
        w |= f2e2m1(b.w * scale) << 28;
        __builtin_nontemporal_store(w, (unsigned*)(out + (i >> 1)));
    }
}

#define BAR()    asm volatile("s_barrier" ::: "memory")
#define WAITV4() asm volatile("s_waitcnt vmcnt(4)" ::: "memory")
#define SCL1 ((int)0x7F7F7F7F)   // E8M0 127 = 2^0 in every byte (identity)

// 32B fp8 fragment read: low 16B at off, high 16B at off^16
__device__ __forceinline__ i32x8 rd32(const char* base, int off) {
    i32x8 r;
    *(i32x4*)&r       = *(const i32x4*)(base + off);
    *((i32x4*)&r + 1) = *(const i32x4*)(base + (off ^ 16));
    return r;
}

// pad a 16B fp4 fragment into the low half of a v8i32 operand
__device__ __forceinline__ i32x8 pad4(i32x4 v) {
    i32x8 r;
    r[0] = v[0]; r[1] = v[1]; r[2] = v[2]; r[3] = v[3];
    r[4] = 0; r[5] = 0; r[6] = 0; r[7] = 0;
    return r;
}

// ------------- 256^2 16-wave mixed fp8(A)/fp4(B) GEMM, static-indexed -------------
__global__ __launch_bounds__(1024, 4)
void lmce_gemm256_kernel(const unsigned char* __restrict__ Xq, const unsigned char* __restrict__ Wq,
                         float* __restrict__ pm, float* __restrict__ pl)
{
    // A: [buf][256 rows][128B] (one 128-elem fp8 K-tile) = 32KB x2
    // B: [buf][256 rows][128B] (one 256-elem fp4 super-tile) = 32KB x2
    __shared__ __align__(16) char lsA[2][256 * 128];
    __shared__ __align__(16) char lsB[2][256 * 128];
    __shared__ float red_m[4][BM];
    __shared__ float red_l[4][BM];
    const char* lsAc = (const char*)lsA;
    const char* lsBc = (const char*)lsB;

    // bijective XCD swizzle: nwg = 8000, divisible by 8
    const int nwg = NT_N * NT_V;
    int orig = blockIdx.x;
    int wg = (orig & 7) * (nwg >> 3) + (orig >> 3);
    int vtile = wg / NT_N;
    int ntile = wg - vtile * NT_N;

    int tid  = threadIdx.x;
    int lane = tid & 63;
    int w    = tid >> 6;          // 0..15
    int wr = w >> 2;              // 0..3 : 64-row A strip
    int wc = w & 3;               // 0..3 : 64-col B strip
    int l31 = lane & 31;
    int kb  = (lane >> 5) * 32;   // A k-byte base within a 64-elem substep
    int kh  = lane >> 5;          // B k-half within a 64-elem substep

    // staging row map: row = j*128 + w*8 + (lane>>3); 16B chunk (lane&7),
    // source col pre-swizzled with the read XOR.
    int scolb = (((lane & 7) ^ ((lane >> 3) & 7)) * 16);
    const char* gAr = (const char*)Xq + (size_t)(ntile * BM + w * 8 + (lane >> 3)) * 4096 + scolb;
    const char* gBr = (const char*)Wq + (size_t)(vtile * BN + w * 8 + (lane >> 3)) * 2048 + scolb;

    // A fragment offsets (fp8): substep ks in 0..1 of the 128-elem tile
    int offA[2][2];
    #pragma unroll
    for (int mi = 0; mi < 2; ++mi)
        #pragma unroll
        for (int ks = 0; ks < 2; ++ks) {
            int rowA = wr * 64 + mi * 32 + l31;
            offA[mi][ks] = rowA * 128 + ((kb + ks * 64) ^ ((rowA & 7) << 4));
        }
    // B fragment offsets (fp4): slot q in 0..3 (64-elem substeps of 256-elem tile)
    int offB[2][4];
    #pragma unroll
    for (int ni = 0; ni < 2; ++ni)
        #pragma unroll
        for (int q = 0; q < 4; ++q) {
            int rowB = wc * 64 + ni * 32 + l31;
            offB[ni][q] = rowB * 128 + ((q * 32 + kh * 16) ^ ((rowB & 7) << 4));
        }

    f32x16 acc[2][2];
    #pragma unroll
    for (int i = 0; i < 2; ++i)
        #pragma unroll
        for (int j = 0; j < 2; ++j)
            #pragma unroll
            for (int r = 0; r < 16; ++r)
                acc[i][j][r] = 0.f;

    #define STAGE_A(BUF, KT)                                                           \
        { _Pragma("unroll")                                                            \
          for (int j_ = 0; j_ < 2; ++j_)                                               \
              __builtin_amdgcn_global_load_lds(                                        \
                  (gas1_u32)(gAr + (size_t)j_ * 524288 + (size_t)(KT) * 128),          \
                  (las3_u32)((char*)lsA + (BUF) * 32768 + j_ * 16384 + w * 1024),      \
                  16, 0, 0); }
    #define STAGE_B(BUF, S)                                                            \
        { _Pragma("unroll")                                                            \
          for (int j_ = 0; j_ < 2; ++j_)                                               \
              __builtin_amdgcn_global_load_lds(                                        \
                  (gas1_u32)(gBr + (size_t)j_ * 262144 + (size_t)(S) * 128),           \
                  (las3_u32)((char*)lsB + (BUF) * 32768 + j_ * 16384 + w * 1024),      \
                  16, 0, 0); }

    // one K=64 substep: A frags (ks static), B slot (q static), 4 MFMAs.
    #define SUBSTEP(AbP, BbP, KS, Q)                                                   \
        {                                                                              \
            i32x8 a0 = rd32(AbP, offA[0][KS]);                                         \
            i32x8 a1 = rd32(AbP, offA[1][KS]);                                         \
            {                                                                          \
                i32x8 b0 = pad4(*(const i32x4*)((BbP) + offB[0][Q]));                  \
                acc[0][0] = __builtin_amdgcn_mfma_scale_f32_32x32x64_f8f6f4(a0, b0, acc[0][0], 0, 4, 0, SCL1, 0, SCL1); \
                acc[1][0] = __builtin_amdgcn_mfma_scale_f32_32x32x64_f8f6f4(a1, b0, acc[1][0], 0, 4, 0, SCL1, 0, SCL1); \
            }                                                                          \
            {                                                                          \
                i32x8 b1 = pad4(*(const i32x4*)((BbP) + offB[1][Q]));                  \
                acc[0][1] = __builtin_amdgcn_mfma_scale_f32_32x32x64_f8f6f4(a0, b1, acc[0][1], 0, 4, 0, SCL1, 0, SCL1); \
                acc[1][1] = __builtin_amdgcn_mfma_scale_f32_32x32x64_f8f6f4(a1, b1, acc[1][1], 0, 4, 0, SCL1, 0, SCL1); \
            }                                                                          \
        }

    // prologue: A0, B0, A1, B1 (8 insts); vmcnt(4) retires A0,B0
    STAGE_A(0, 0); STAGE_B(0, 0);
    STAGE_A(1, 1); STAGE_B(1, 1);
    WAITV4();
    BAR();

    for (int t = 0; t < NKT; t += 2) {
        int s  = t >> 1;                       // B super-tile index
        const char* BbP = lsBc + (s & 1) * 32768;   // runtime base (ptr math, ok)

        // ---- even iteration (tile t): A buf0, B half 0 (q = 0,1)
        SUBSTEP(lsAc,        BbP, 0, 0);
        SUBSTEP(lsAc,        BbP, 1, 1);
        BAR();                                 // all reads of A buf0 retired
        {
            int ta = (t + 2 < NKT) ? t + 2 : NKT - 1;
            STAGE_A(0, ta);                    // A(t+2) -> retired buf0
        }
        // outstanding: A(t+1)2, B(s+1)2, A(t+2)2 = 6 -> vmcnt(4) retires A(t+1)
        WAITV4();
        BAR();

        // ---- odd iteration (tile t+1): A buf1, B half 1 (q = 2,3)
        SUBSTEP(lsAc + 32768, BbP, 0, 2);
        SUBSTEP(lsAc + 32768, BbP, 1, 3);
        BAR();                                 // reads of A buf1 + B buf retired
        {
            int ta = (t + 3 < NKT) ? t + 3 : NKT - 1;
            STAGE_A(1, ta);                    // A(t+3) -> retired buf1
            int s2 = (s + 2 < 16) ? s + 2 : 15;
            STAGE_B(s & 1, s2);                // B(s+2) -> retired B buf
        }
        // outstanding: B(s+1)2, A(t+2)2, A(t+3)2, B(s+2)2 = 8
        // vmcnt(4) retires B(s+1)+A(t+2): exactly what tile t+2 needs.
        WAITV4();
        BAR();
    }

    __syncthreads();   // full drain before epilogue

    // Epilogue: per-row max and sumexp over this block's 256 cols.
    // 32x32 C/D layout: col = lane&31, row = (r&3) + 8*(r>>2) + 4*(lane>>5).
    // Unscale logits by 2^-6 (W was stored x64) -- exact power of two.
    const float inv64 = 0.015625f;
    #pragma unroll
    for (int mi = 0; mi < 2; ++mi) {
        #pragma unroll
        for (int r = 0; r < 16; ++r) {
            float v0 = acc[mi][0][r] * inv64;
            float v1 = acc[mi][1][r] * inv64;
            float mx = fmaxf(v0, v1);
            #pragma unroll
            for (int s = 1; s < 32; s <<= 1)
                mx = fmaxf(mx, __shfl_xor(mx, s, 64));
            float se = __expf(v0 - mx) + __expf(v1 - mx);
            #pragma unroll
            for (int s = 1; s < 32; s <<= 1)
                se += __shfl_xor(se, s, 64);
            if (l31 == 0) {
                int rloc = wr * 64 + mi * 32 + (r & 3) + 8 * (r >> 2) + 4 * (lane >> 5);
                red_m[wc][rloc] = mx;
                red_l[wc][rloc] = se;
            }
        }
    }
    __syncthreads();
    if (tid < BM) {
        float mm = red_m[0][tid], ll = red_l[0][tid];
        #pragma unroll
        for (int p = 1; p < 4; ++p) {
            float m2 = red_m[p][tid], l2 = red_l[p][tid];
            float m3 = fmaxf(mm, m2);
            ll = ll * __expf(mm - m3) + l2 * __expf(m2 - m3);
            mm = m3;
        }
        size_t idx = (size_t)vtile * N_ROWS + (size_t)(ntile * BM + tid);
        pm[idx] = mm;
        pl[idx] = ll;
    }
    #undef STAGE_A
    #undef STAGE_B
    #undef SUBSTEP
}

// tgt[row] = dot(x[row], W[y[row]]) in fp32 (exact vs reference)
__global__ void lmce_tgt_kernel(const float* __restrict__ X, const float* __restrict__ W,
                                const int* __restrict__ y, float* __restrict__ tgt)
{
    int row = blockIdx.x;
    int tid = threadIdx.x;
    int yv = y[row];
    float s = 0.f;
    if (yv >= 0 && yv < V_DIM) {
        const float* xr = X + (size_t)row * H_DIM;
        const float* wrow = W + (size_t)yv * H_DIM;
        #pragma unroll
        for (int j = 0; j < 4; ++j) {
            int idx = (tid + j * 256) * 4;
            f32x4 a = *(const f32x4*)(xr + idx);
            f32x4 b = *(const f32x4*)(wrow + idx);
            s += a.x * b.x + a.y * b.y + a.z * b.z + a.w * b.w;
        }
    }
    #pragma unroll
    for (int sh = 1; sh < 64; sh <<= 1) s += __shfl_xor(s, sh, 64);
    __shared__ float sred[4];
    if ((tid & 63) == 0) sred[tid >> 6] = s;
    __syncthreads();
    if (tid == 0) tgt[row] = sred[0] + sred[1] + sred[2] + sred[3];
}

// merge NT_V per-vtile (m,l) partials per row -> lse[row]
__global__ void lmce_lse_kernel(const float* __restrict__ pm, const float* __restrict__ pl,
                                float* __restrict__ lse)
{
    int tid = threadIdx.x;
    int row = blockIdx.x * 64 + (tid & 63);
    int part = tid >> 6;               // 0..3, each scans NT_V/4 = 125 vtiles
    const int per = NT_V / 4;
    float m = -INFINITY, l = 0.f;
    for (int vt = part * per; vt < (part + 1) * per; ++vt) {
        size_t idx = (size_t)vt * N_ROWS + row;
        float m2 = pm[idx], l2 = pl[idx];
        float mm = fmaxf(m, m2);
        l = l * __expf(m - mm) + l2 * __expf(m2 - mm);
        m = mm;
    }
    __shared__ float sm[4][64], sl[4][64];
    sm[part][tid & 63] = m;
    sl[part][tid & 63] = l;
    __syncthreads();
    if (tid < 64) {
        float M = sm[0][tid], L = sl[0][tid];
        #pragma unroll
        for (int p = 1; p < 4; ++p) {
            float m2 = sm[p][tid], l2 = sl[p][tid];
            float mm = fmaxf(M, m2);
            L = L * __expf(M - mm) + l2 * __expf(m2 - mm);
            M = mm;
        }
        lse[blockIdx.x * 64 + tid] = M + logf(L);
    }
}

__global__ void lmce_final_kernel(const float* __restrict__ lse, const float* __restrict__ tgt,
                                  const int* __restrict__ y, float* __restrict__ out)
{
    int tid = threadIdx.x;
    float s = 0.f, c = 0.f;
    for (int i = tid; i < N_ROWS; i += 256) {
        if (y[i] != IGNORE_INDEX) {
            s += lse[i] - tgt[i];
            c += 1.f;
        }
    }
    #pragma unroll
    for (int sh = 1; sh < 64; sh <<= 1) {
        s += __shfl_xor(s, sh, 64);
        c += __shfl_xor(c, sh, 64);
    }
    __shared__ float ss[4], cc[4];
    if ((tid & 63) == 0) { ss[tid >> 6] = s; cc[tid >> 6] = c; }
    __syncthreads();
    if (tid == 0) {
        float S = ss[0] + ss[1] + ss[2] + ss[3];
        float C = cc[0] + cc[1] + cc[2] + cc[3];
        out[0] = S / fmaxf(C, 1.f);
    }
}

extern "C" void kernel_launch(void* const* d_in, const int* in_sizes, int n_in,
                              void* d_out, int out_size, void* d_ws, size_t ws_size,
                              hipStream_t stream)
{
    const float* X = (const float*)d_in[0];   // [4096, 4096] fp32
    const int*   y = (const int*)d_in[1];     // [4096] labels
    const float* W = (const float*)d_in[2];   // [128000, 4096] fp32
    float* out = (float*)d_out;

    char* ws = (char*)d_ws;
    const size_t OFF_PL  = 16384000;
    const size_t OFF_TGT = 32768000;
    const size_t OFF_LSE = 32784384;
    const size_t OFF_XQ  = 32800768;                 // 16 MB fp8 X
    const size_t OFF_WQ  = OFF_XQ + 16777216;        // 256 MB fp4 W (x64 scaled)

    float* pm  = (float*)ws;
    float* pl  = (float*)(ws + OFF_PL);
    float* tgt = (float*)(ws + OFF_TGT);
    float* lse = (float*)(ws + OFF_LSE);
    unsigned char* Xq = (unsigned char*)(ws + OFF_XQ);
    unsigned char* Wq = (unsigned char*)(ws + OFF_WQ);

    cvt_f32_fp4_kernel<<<4096, 256, 0, stream>>>(W, Wq, (size_t)V_DIM * H_DIM, 64.0f);
    cvt_f32_fp8_kernel<<<512, 256, 0, stream>>>(X, Xq, (size_t)N_ROWS * H_DIM, 1.0f);
    lmce_gemm256_kernel<<<NT_N * NT_V, 1024, 0, stream>>>(Xq, Wq, pm, pl);
    lmce_tgt_kernel<<<N_ROWS, 256, 0, stream>>>(X, W, y, tgt);
    lmce_lse_kernel<<<N_ROWS / 64, 256, 0, stream>>>(pm, pl, lse);
    lmce_final_kernel<<<1, 256, 0, stream>>>(lse, tgt, y, out);
}